// Round 13
// baseline (1850.132 us; speedup 1.0000x reference)
//
#include <hip/hip_runtime.h>
#include <cstdint>
#include <cstddef>

typedef _Float16 h2_t __attribute__((ext_vector_type(2)));
typedef unsigned int uint;
typedef unsigned short ushortt;

#define BB 128
#define TT 512

// ---- ws layout (bytes) ----
#define OFF_W0   0u           // 393216  (layer0 W_hh image, 24 chunks x 1024 quads)
#define OFF_W1   393216u      // 393216  (layer1)
#define OFF_PI0  786432u      // 98304
#define OFF_PI1  884736u      // 393216
#define OFF_H2O  1277952u     // 131072
#define OFF_H1   1409024u     // 33554432
#define OFF_GX   34963456u    // 100663296 (end ~135.6 MB)

__device__ __forceinline__ uint pack2(float a, float b){
  h2_t h; h.x = (_Float16)a; h.y = (_Float16)b;
  return __builtin_bit_cast(uint, h);
}
__device__ __forceinline__ float f16f(ushortt s){
  return (float)__builtin_bit_cast(_Float16, s);
}
__device__ __forceinline__ ushortt ff16(float f){
  return __builtin_bit_cast(ushortt, (_Float16)f);
}
__device__ __forceinline__ float dot2(uint w, uint h, float acc){
  return __builtin_amdgcn_fdot2(__builtin_bit_cast(h2_t, w),
                                __builtin_bit_cast(h2_t, h), acc, false);
}
template<int CTRL>
__device__ __forceinline__ float dpp_addf(float x){
  int p = __builtin_amdgcn_update_dpp(0, __float_as_int(x), CTRL, 0xF, 0xF, true);
  return x + __int_as_float(p);
}
// sum over 4-lane quads, result in all 4 lanes (verified r4-r8)
__device__ __forceinline__ float red4(float x){
  x = dpp_addf<0xB1>(x); x = dpp_addf<0x4E>(x);
  return x;
}

// =================== prep: pack fp32 weights -> f16 images ===================
// W_hh image (r5/r7-verified REC org, all 24 chunks in one image):
// dword j: e=j&3, tid=(j>>2)&1023, c=(j>>2)>>10. Thread (q=tid&7, u=tid>>3),
// chunk c=r*4+k4, r=g*2+s: row=g*256+2u+s, col=32q+8k4+2e (+1).
__global__ void prep_kernel(const float* __restrict__ W_ih0, const float* __restrict__ W_hh0,
                            const float* __restrict__ W_ih1, const float* __restrict__ W_hh1,
                            uint* __restrict__ W0, uint* __restrict__ W1,
                            uint* __restrict__ PI0, uint* __restrict__ PI1)
{
  int i = blockIdx.x*256 + threadIdx.x;
  if (i < 196608) {
    const int layer = (i >= 98304) ? 1 : 0;
    const float* W = layer ? W_hh1 : W_hh0;
    int j = layer ? (i - 98304) : i;
    int e = j&3, r2 = j>>2;
    int tid = r2 & 1023, c = r2 >> 10;
    int q = tid&7, u = tid>>3, k4 = c&3, r = c>>2;
    int g = r>>1, s = r&1;
    int row = g*256 + 2*u + s, col = 32*q + 8*k4 + 2*e;
    uint val = pack2(W[row*256+col], W[row*256+col+1]);
    (layer ? W1 : W0)[j] = val;
  } else if (i < 221184) {
    int j2 = i - 196608;
    int jj = j2 & 255, rc = j2 >> 8;
    int ci = rc & 31, r = rc >> 5;
    PI0[j2] = pack2(W_ih0[(r*256+jj)*64 + 2*ci], W_ih0[(r*256+jj)*64 + 2*ci + 1]);
  } else if (i < 319488) {
    int j3 = i - 221184;
    int tid = j3 & 1023, rc = j3 >> 10;
    int ci = rc & 31, r = rc >> 5;
    int kq = tid & 3, jj = tid >> 2;
    int col = 64*kq + 2*ci;
    PI1[j3] = pack2(W_ih1[(r*256+jj)*256 + col], W_ih1[(r*256+jj)*256 + col + 1]);
  }
}

// =================== GEMM0: gx0 = W_ih0 . x + biases (unchanged) ===================
__global__ __launch_bounds__(512) void gemm0_kernel(
    const float* __restrict__ x, const uint* __restrict__ PI0,
    const float* __restrict__ b_ih0, const float* __restrict__ b_hh0,
    ushortt* __restrict__ gx)
{
  const int blk = blockIdx.x;
  const int b = blk >> 4, t0 = (blk & 15) * 32;
  const int tid = threadIdx.x;
  const int j = tid & 255, th = tid >> 8;
  __shared__ uint xs[32*32];
  {
    float4 v = ((const float4*)x)[((size_t)b*TT + t0 + (tid>>4))*16 + (tid&15)];
    xs[(tid>>4)*32 + (tid&15)*2]     = pack2(v.x, v.y);
    xs[(tid>>4)*32 + (tid&15)*2 + 1] = pack2(v.z, v.w);
  }
  uint w[96];
  #pragma unroll
  for (int rc = 0; rc < 96; ++rc) w[rc] = PI0[rc*256 + j];
  const float br = b_ih0[j] + b_hh0[j];
  const float bz = b_ih0[256+j] + b_hh0[256+j];
  const float bn = b_ih0[512+j];
  __syncthreads();
  ushortt* gout = gx + ((size_t)b*TT + t0 + th*16)*768;
  #pragma unroll 1
  for (int tt = 0; tt < 16; ++tt) {
    const uint* xr = xs + (th*16 + tt)*32;
    float ar=0.f, az=0.f, an=0.f;
    #pragma unroll
    for (int c = 0; c < 32; ++c) {
      uint xv = xr[c];
      ar = dot2(w[c],    xv, ar);
      az = dot2(w[32+c], xv, az);
      an = dot2(w[64+c], xv, an);
    }
    gout[j]     = ff16(ar + br);
    gout[256+j] = ff16(az + bz);
    gout[512+j] = ff16(an + bn);
    gout += 768;
  }
}

// =================== GEMM1: gx1 = W_ih1 . h1 + biases (unchanged) ===================
__global__ __launch_bounds__(1024, 4) void gemm1_kernel(
    const uint* __restrict__ h1, const uint* __restrict__ PI1,
    const float* __restrict__ b_ih1, const float* __restrict__ b_hh1,
    ushortt* __restrict__ gx)
{
  const int blk = blockIdx.x;
  const int b = blk >> 5, t0 = (blk & 31) * 16;
  const int tid = threadIdx.x;
  const int kq = tid & 3, j = tid >> 2;
  __shared__ uint hsT[16*144];
  {
    uint2 v = ((const uint2*)(h1 + ((size_t)b*TT + t0)*128))[tid];
    int f = 2*tid, tp = f>>7, c = f&127, s = c>>2, e = c&3;
    *(uint2*)&hsT[tp*144 + (s + (s>>3))*4 + e] = v;
  }
  uint w[96];
  #pragma unroll
  for (int rc = 0; rc < 96; ++rc) w[rc] = PI1[rc*1024 + tid];
  const float br = b_ih1[j] + b_hh1[j];
  const float bz = b_ih1[256+j] + b_hh1[256+j];
  const float bn = b_ih1[512+j];
  __syncthreads();
  ushortt* gout = gx + ((size_t)b*TT + t0)*768;
  #pragma unroll 1
  for (int tt = 0; tt < 16; ++tt) {
    const uint4* hr = (const uint4*)&hsT[tt*144];
    float ar=0.f, az=0.f, an=0.f;
    #pragma unroll
    for (int i = 0; i < 8; ++i) {
      uint4 hv = hr[9*kq + i];
      ar = dot2(w[4*i],hv.x,ar);    ar = dot2(w[4*i+1],hv.y,ar);
      ar = dot2(w[4*i+2],hv.z,ar);  ar = dot2(w[4*i+3],hv.w,ar);
      az = dot2(w[32+4*i],hv.x,az); az = dot2(w[32+4*i+1],hv.y,az);
      az = dot2(w[32+4*i+2],hv.z,az); az = dot2(w[32+4*i+3],hv.w,az);
      an = dot2(w[64+4*i],hv.x,an); an = dot2(w[64+4*i+1],hv.y,an);
      an = dot2(w[64+4*i+2],hv.z,an); an = dot2(w[64+4*i+3],hv.w,an);
    }
    ar = red4(ar); az = red4(az); an = red4(an);
    if (kq == 0) {
      gout[j]     = ff16(ar + br);
      gout[256+j] = ff16(az + bz);
      gout[512+j] = ff16(an + bn);
    }
    gout += 768;
  }
}

// =================== REC: full-asm inner loop, weights pinned in v0-v95 ===================
// r23 = r22 (passing, 753 us/rec) + 1-step gx prefetch:
// r22 issued the 3 gx ushort loads at the top of the step and drained them with
// s_waitcnt vmcnt(0) mid-step (~220 wave-issue cycles of slack vs 200-400cy L2
// latency; on the L0 path the same vmcnt(0) also waited on the prior h1 store).
// Now the loads for step t+1 are issued inside step t's serial gate chain
// (idle issue slots), guarded by cnt<511 so the final step doesn't read past
// the GX region; the prolog issues step 0's loads. The consuming vmcnt(0) then
// waits on ~3000cy-old loads -> zero stall.
// Register map: v0-v95 weights (loaded once), v96-v103 h ping-pong, v104-109
// accumulators, v110-v125 temps. Dbuf toggle in SGPR (r20 fix).
#define A(s) s "\n\t"
#define WL(a,b) A("global_load_dwordx4 v[" #a ":" #b "], v125, %[wi]") A("v_add_u32 v125, 0x4000, v125")
#define D6(w0,w1,w2,w3,w4,w5,hk) \
  A("v_dot2_f32_f16 v104, v" #w0 ", v" #hk ", v104") \
  A("v_dot2_f32_f16 v105, v" #w1 ", v" #hk ", v105") \
  A("v_dot2_f32_f16 v106, v" #w2 ", v" #hk ", v106") \
  A("v_dot2_f32_f16 v107, v" #w3 ", v" #hk ", v107") \
  A("v_dot2_f32_f16 v108, v" #w4 ", v" #hk ", v108") \
  A("v_dot2_f32_f16 v109, v" #w5 ", v" #hk ", v109")
#define RED_P1(a) \
  A("v_add_f32 v" #a ", v" #a ", v" #a " quad_perm:[1,0,3,2] row_mask:0xf bank_mask:0xf")
#define RED_P2(a) \
  A("v_add_f32 v" #a ", v" #a ", v" #a " quad_perm:[2,3,0,1] row_mask:0xf bank_mask:0xf")

#define REC_PROLOG \
  A("v_and_b32 v118, 7, %[tid]")            /* q */ \
  A("v_lshrrev_b32 v121, 3, %[tid]")        /* u */ \
  A("v_and_b32 v119, 1, v118")              /* odd */ \
  A("v_lshl_add_u32 v122, v121, 1, v118")   /* j = 2u+q */ \
  A("v_min_u32 v122, 0xff, v122")           /* clamp for q>=2 lanes */ \
  A("v_lshlrev_b32 v110, 1, v122")          /* gx byte voff = 2j */ \
  A("v_lshlrev_b32 v123, 2, v122") \
  A("global_load_dword v120, v123, %[bh] offset:2048")  /* bhn = b_hh[512+j] */ \
  A("global_load_ushort v111, v110, %[gx]")             /* gx prefetch t=0 */ \
  A("global_load_ushort v112, v110, %[gx] offset:512") \
  A("global_load_ushort v113, v110, %[gx] offset:1024") \
  A("v_mul_u32_u24 v115, 80, v118") \
  A("v_add_u32 v115, %[hb], v115")          /* rd addr (buf0): 80q */ \
  A("v_lshrrev_b32 v124, 4, v121") \
  A("v_lshl_add_u32 v124, v124, 2, v121")   /* u + 4*(u>>4) */ \
  A("v_lshlrev_b32 v124, 2, v124") \
  A("v_add_u32 v124, 0x280, v124") \
  A("v_add_u32 v116, %[hb], v124")          /* wr addr (buf1) */ \
  A("v_mov_b32 v114, 0")                    /* h_old */ \
  A("s_mov_b32 %[tog], 0x280")              /* dbuf toggle +/-640 (SGPR) */ \
  A("v_lshlrev_b32 v125, 4, %[tid]") \
  WL(0,3) WL(4,7) WL(8,11) WL(12,15) WL(16,19) WL(20,23) \
  WL(24,27) WL(28,31) WL(32,35) WL(36,39) WL(40,43) WL(44,47) \
  WL(48,51) WL(52,55) WL(56,59) WL(60,63) WL(64,67) WL(68,71) \
  WL(72,75) WL(76,79) WL(80,83) WL(84,87) WL(88,91) WL(92,95) \
  A("s_waitcnt vmcnt(0)") \
  A("s_mov_b32 %[cnt], 0")

#define REC_STEP_A \
  A("1:") \
  A("ds_read_b128 v[96:99], v115") \
  A("ds_read_b128 v[100:103], v115 offset:16") \
  A("v_mov_b32 v104, 0") A("v_mov_b32 v105, 0") A("v_mov_b32 v106, 0") \
  A("v_mov_b32 v107, 0") A("v_mov_b32 v108, 0") A("v_mov_b32 v109, 0") \
  A("s_waitcnt lgkmcnt(1)") \
  D6(0,16,32,48,64,80,96) D6(1,17,33,49,65,81,97) \
  D6(2,18,34,50,66,82,98) D6(3,19,35,51,67,83,99) \
  A("ds_read_b128 v[96:99], v115 offset:32") \
  A("s_waitcnt lgkmcnt(1)") \
  D6(4,20,36,52,68,84,100) D6(5,21,37,53,69,85,101) \
  D6(6,22,38,54,70,86,102) D6(7,23,39,55,71,87,103) \
  A("ds_read_b128 v[100:103], v115 offset:48") \
  A("s_waitcnt lgkmcnt(1)") \
  D6(8,24,40,56,72,88,96) D6(9,25,41,57,73,89,97) \
  D6(10,26,42,58,74,90,98) D6(11,27,43,59,75,91,99) \
  A("s_waitcnt lgkmcnt(0)") \
  D6(12,28,44,60,76,92,100) D6(13,29,45,61,77,93,101) \
  D6(14,30,46,62,78,94,102) D6(15,31,47,63,79,95,103) \
  RED_P1(104) RED_P1(105) RED_P1(106) RED_P1(107) RED_P1(108) RED_P1(109) \
  RED_P2(104) RED_P2(105) RED_P2(106) RED_P2(107) RED_P2(108) RED_P2(109) \
  A("ds_swizzle_b32 v96, v104 offset:0x101f") \
  A("ds_swizzle_b32 v97, v105 offset:0x101f") \
  A("ds_swizzle_b32 v98, v106 offset:0x101f") \
  A("ds_swizzle_b32 v99, v107 offset:0x101f") \
  A("ds_swizzle_b32 v100, v108 offset:0x101f") \
  A("ds_swizzle_b32 v101, v109 offset:0x101f") \
  A("s_waitcnt lgkmcnt(0)") \
  A("v_add_f32 v104, v104, v96") A("v_add_f32 v105, v105, v97") \
  A("v_add_f32 v106, v106, v98") A("v_add_f32 v107, v107, v99") \
  A("v_add_f32 v108, v108, v100") A("v_add_f32 v109, v109, v101") \
  A("v_cmp_eq_u32 vcc, 1, v119") \
  A("v_cndmask_b32 v121, v104, v105, vcc")  /* Sr */ \
  A("v_cndmask_b32 v122, v106, v107, vcc")  /* Sz */ \
  A("v_cndmask_b32 v123, v108, v109, vcc")  /* Sn */ \
  A("s_waitcnt vmcnt(0)") \
  A("v_cvt_f32_f16 v124, v111") \
  A("v_add_f32 v121, v121, v124") \
  A("v_mul_f32 v121, 0xbfb8aa3b, v121") \
  A("v_exp_f32 v121, v121") \
  A("s_nop 1") \
  A("v_add_f32 v121, 1.0, v121") \
  A("v_rcp_f32 v121, v121")                 /* r */ \
  A("v_cvt_f32_f16 v124, v112") \
  A("v_add_f32 v122, v122, v124") \
  A("v_mul_f32 v122, 0xbfb8aa3b, v122") \
  A("v_exp_f32 v122, v122") \
  A("s_nop 1") \
  A("v_add_f32 v122, 1.0, v122") \
  A("v_rcp_f32 v122, v122")                 /* z */ \
  A("v_add_f32 v123, v123, v120") \
  A("v_cvt_f32_f16 v124, v113") \
  A("s_nop 1") \
  A("v_fma_f32 v123, v121, v123, v124")     /* pre-n */ \
  A("s_cmp_lt_u32 %[cnt], 511")             /* gx prefetch for t+1 (skip at t=511) */ \
  A("s_cbranch_scc0 2f") \
  A("v_add_u32 v110, 0x600, v110") \
  A("global_load_ushort v111, v110, %[gx]") \
  A("global_load_ushort v112, v110, %[gx] offset:512") \
  A("global_load_ushort v113, v110, %[gx] offset:1024") \
  A("2:") \
  A("v_max_f32 v123, 0xc1700000, v123") \
  A("v_min_f32 v123, 0x41700000, v123") \
  A("v_mul_f32 v123, 0x4038aa3b, v123") \
  A("v_exp_f32 v123, v123") \
  A("s_nop 1") \
  A("v_add_f32 v124, 1.0, v123") \
  A("v_rcp_f32 v124, v124") \
  A("v_add_f32 v123, -1.0, v123") \
  A("s_nop 1") \
  A("v_mul_f32 v123, v123, v124")           /* n */ \
  A("v_sub_f32 v124, v114, v123") \
  A("v_fma_f32 v114, v122, v124, v123")     /* h_old = hn */ \
  A("v_cvt_f16_f32 v125, v114") \
  A("v_and_b32 v125, 0xffff, v125") \
  A("v_mov_b32 v124, v114 quad_perm:[1,0,3,2] row_mask:0xf bank_mask:0xf") \
  A("v_cvt_f16_f32 v124, v124") \
  A("v_lshlrev_b32 v124, 16, v124") \
  A("v_or_b32 v125, v124, v125")            /* hv2 = pack2(hn_even, hn_odd) */ \
  A("v_cmp_eq_u32 vcc, 0, v118") \
  A("s_and_saveexec_b64 %[sx], vcc") \
  A("ds_write_b32 v116, v125")

#define REC_STEP_B \
  A("s_mov_b64 exec, -1") \
  A("v_add_u32 v115, %[tog], v115")         /* rd buf toggle (+/-640) */ \
  A("v_subrev_u32 v116, %[tog], v116")      /* wr buf toggle (-/+640) */ \
  A("s_sub_u32 %[tog], 0, %[tog]") \
  A("s_waitcnt lgkmcnt(0)") \
  A("s_barrier") \
  A("s_add_u32 %[cnt], %[cnt], 1") \
  A("s_cmp_lt_u32 %[cnt], 512") \
  A("s_cbranch_scc1 1b")

#define REC_CLOBBERS \
  "memory","vcc","scc", \
  "v0","v1","v2","v3","v4","v5","v6","v7","v8","v9","v10","v11","v12","v13","v14","v15", \
  "v16","v17","v18","v19","v20","v21","v22","v23","v24","v25","v26","v27","v28","v29","v30","v31", \
  "v32","v33","v34","v35","v36","v37","v38","v39","v40","v41","v42","v43","v44","v45","v46","v47", \
  "v48","v49","v50","v51","v52","v53","v54","v55","v56","v57","v58","v59","v60","v61","v62","v63", \
  "v64","v65","v66","v67","v68","v69","v70","v71","v72","v73","v74","v75","v76","v77","v78","v79", \
  "v80","v81","v82","v83","v84","v85","v86","v87","v88","v89","v90","v91","v92","v93","v94","v95", \
  "v96","v97","v98","v99","v100","v101","v102","v103","v104","v105","v106","v107","v108","v109", \
  "v110","v111","v112","v113","v114","v115","v116","v117","v118","v119","v120","v121","v122","v123","v124","v125"

template<bool IS_L0>
__global__ __launch_bounds__(1024) void rec_kernel(
    const uint* __restrict__ Wimg, const ushortt* __restrict__ GX,
    const float* __restrict__ b_hh,
    uint* __restrict__ h1, float* __restrict__ h2o)
{
  __shared__ __align__(16) uint hb[320];    // 2 x 160-uint padded h dbuf (r7 layout)
  const uint tid = threadIdx.x;
  if (tid < 320) hb[tid] = 0;
  __syncthreads();
  const uint hbaddr = (uint)(uintptr_t)(&hb[0]);
  const int b = blockIdx.x;
  const ushortt* gxp = GX + (size_t)b*TT*768;
  uint cnt, tog; unsigned long long sx;
  if constexpr (IS_L0) {
    uint* h1p = h1 + (size_t)b*TT*128;
    asm volatile(
      REC_PROLOG
      A("v_lshlrev_b32 v117, 2, v121")      /* h1 voff = u*4 */
      REC_STEP_A
      A("global_store_dword v117, v125, %[h1]")
      A("v_add_u32 v117, 0x200, v117")
      REC_STEP_B
      : [cnt]"=&s"(cnt), [sx]"=&s"(sx), [tog]"=&s"(tog)
      : [tid]"v"(tid), [hb]"v"(hbaddr), [gx]"s"(gxp), [wi]"s"(Wimg),
        [bh]"s"(b_hh), [h1]"s"(h1p)
      : REC_CLOBBERS);
  } else {
    float* hop = h2o + (size_t)b*256;
    asm volatile(
      REC_PROLOG
      A("v_lshlrev_b32 v117, 2, v122")      /* h2o voff = j*4 */
      REC_STEP_A
      REC_STEP_B
      A("v_cmp_gt_u32 vcc, 2, v118")        /* q < 2 */
      A("s_and_saveexec_b64 %[sx], vcc")
      A("global_store_dword v117, v114, %[ho]")
      A("s_mov_b64 exec, -1")
      : [cnt]"=&s"(cnt), [sx]"=&s"(sx), [tog]"=&s"(tog)
      : [tid]"v"(tid), [hb]"v"(hbaddr), [gx]"s"(gxp), [wi]"s"(Wimg),
        [bh]"s"(b_hh), [ho]"s"(hop)
      : REC_CLOBBERS);
  }
}

// =================== MLP head (unchanged) ===================
__global__ __launch_bounds__(128) void mlp_kernel(
    const float* __restrict__ h2, const float* __restrict__ W1,
    const float* __restrict__ b1, const float* __restrict__ W2,
    const float* __restrict__ b2, float* __restrict__ out)
{
  __shared__ float hls[256];
  __shared__ float red[128];
  const int b = blockIdx.x, tid = threadIdx.x;
  if (tid < 64) ((float4*)hls)[tid] = ((const float4*)(h2 + (size_t)b*256))[tid];
  __syncthreads();
  float acc = b1[tid];
  const float4* w4 = (const float4*)(W1 + (size_t)tid*256);
  const float4* h4 = (const float4*)hls;
  #pragma unroll 8
  for (int k = 0; k < 64; ++k) {
    float4 w = w4[k]; float4 h = h4[k];
    acc = fmaf(w.x,h.x,acc); acc = fmaf(w.y,h.y,acc);
    acc = fmaf(w.z,h.z,acc); acc = fmaf(w.w,h.w,acc);
  }
  red[tid] = fmaxf(acc, 0.0f) * W2[tid];
  __syncthreads();
  for (int s = 64; s > 0; s >>= 1) {
    if (tid < s) red[tid] += red[tid + s];
    __syncthreads();
  }
  if (tid == 0) out[b] = red[0] + b2[0];
}

extern "C" void kernel_launch(void* const* d_in, const int* in_sizes, int n_in,
                              void* d_out, int out_size, void* d_ws, size_t ws_size,
                              hipStream_t stream)
{
  const float* x     = (const float*)d_in[0];
  const float* W_ih0 = (const float*)d_in[1];
  const float* W_hh0 = (const float*)d_in[2];
  const float* b_ih0 = (const float*)d_in[3];
  const float* b_hh0 = (const float*)d_in[4];
  const float* W_ih1 = (const float*)d_in[5];
  const float* W_hh1 = (const float*)d_in[6];
  const float* b_ih1 = (const float*)d_in[7];
  const float* b_hh1 = (const float*)d_in[8];
  const float* W1    = (const float*)d_in[9];
  const float* b1    = (const float*)d_in[10];
  const float* W2    = (const float*)d_in[11];
  const float* b2    = (const float*)d_in[12];

  char* ws = (char*)d_ws;
  uint*    W0i  = (uint*)(ws + OFF_W0);
  uint*    W1i  = (uint*)(ws + OFF_W1);
  uint*    PI0  = (uint*)(ws + OFF_PI0);
  uint*    PI1  = (uint*)(ws + OFF_PI1);
  float*   H2O  = (float*)(ws + OFF_H2O);
  uint*    H1   = (uint*)(ws + OFF_H1);
  ushortt* GX   = (ushortt*)(ws + OFF_GX);

  prep_kernel<<<1248, 256, 0, stream>>>(W_ih0, W_hh0, W_ih1, W_hh1,
                                        W0i, W1i, PI0, PI1);
  gemm0_kernel<<<2048, 512, 0, stream>>>(x, PI0, b_ih0, b_hh0, GX);
  rec_kernel<true><<<BB, 1024, 0, stream>>>(W0i, GX, b_hh0, H1, nullptr);
  gemm1_kernel<<<4096, 1024, 0, stream>>>(H1, PI1, b_ih1, b_hh1, GX);
  rec_kernel<false><<<BB, 1024, 0, stream>>>(W1i, GX, b_hh1, nullptr, H2O);
  mlp_kernel<<<BB, 128, 0, stream>>>(H2O, W1, b1, W2, b2, (float*)d_out);
}

// Round 14
// 1799.837 us; speedup vs baseline: 1.0279x; 1.0279x over previous
//
#include <hip/hip_runtime.h>
#include <cstdint>
#include <cstddef>

typedef _Float16 h2_t __attribute__((ext_vector_type(2)));
typedef unsigned int uint;
typedef unsigned short ushortt;

#define BB 128
#define TT 512

// ---- ws layout (bytes) ----
#define OFF_W0   0u           // 393216  (layer0 W_hh image, 24 chunks x 1024 quads)
#define OFF_W1   393216u      // 393216  (layer1)
#define OFF_PI0  786432u      // 98304
#define OFF_PI1  884736u      // 393216
#define OFF_H2O  1277952u     // 131072
#define OFF_H1   1409024u     // 33554432
#define OFF_GX   34963456u    // 100663296 (end ~135.6 MB)

__device__ __forceinline__ uint pack2(float a, float b){
  h2_t h; h.x = (_Float16)a; h.y = (_Float16)b;
  return __builtin_bit_cast(uint, h);
}
__device__ __forceinline__ float f16f(ushortt s){
  return (float)__builtin_bit_cast(_Float16, s);
}
__device__ __forceinline__ ushortt ff16(float f){
  return __builtin_bit_cast(ushortt, (_Float16)f);
}
__device__ __forceinline__ float dot2(uint w, uint h, float acc){
  return __builtin_amdgcn_fdot2(__builtin_bit_cast(h2_t, w),
                                __builtin_bit_cast(h2_t, h), acc, false);
}
template<int CTRL>
__device__ __forceinline__ float dpp_addf(float x){
  int p = __builtin_amdgcn_update_dpp(0, __float_as_int(x), CTRL, 0xF, 0xF, true);
  return x + __int_as_float(p);
}
// sum over 4-lane quads, result in all 4 lanes (verified r4-r8)
__device__ __forceinline__ float red4(float x){
  x = dpp_addf<0xB1>(x); x = dpp_addf<0x4E>(x);
  return x;
}

// =================== prep: pack fp32 weights -> f16 images ===================
// W_hh image (r5/r7-verified REC org, all 24 chunks in one image):
// dword j: e=j&3, tid=(j>>2)&1023, c=(j>>2)>>10. Thread (q=tid&7, u=tid>>3),
// chunk c=r*4+k4, r=g*2+s: row=g*256+2u+s, col=32q+8k4+2e (+1).
// r24: REC threads remap lane->(q,u) (q=bits013, u=bits245+wave) and load the
// image entry old_tid = u*8+q -- image layout itself unchanged.
__global__ void prep_kernel(const float* __restrict__ W_ih0, const float* __restrict__ W_hh0,
                            const float* __restrict__ W_ih1, const float* __restrict__ W_hh1,
                            uint* __restrict__ W0, uint* __restrict__ W1,
                            uint* __restrict__ PI0, uint* __restrict__ PI1)
{
  int i = blockIdx.x*256 + threadIdx.x;
  if (i < 196608) {
    const int layer = (i >= 98304) ? 1 : 0;
    const float* W = layer ? W_hh1 : W_hh0;
    int j = layer ? (i - 98304) : i;
    int e = j&3, r2 = j>>2;
    int tid = r2 & 1023, c = r2 >> 10;
    int q = tid&7, u = tid>>3, k4 = c&3, r = c>>2;
    int g = r>>1, s = r&1;
    int row = g*256 + 2*u + s, col = 32*q + 8*k4 + 2*e;
    uint val = pack2(W[row*256+col], W[row*256+col+1]);
    (layer ? W1 : W0)[j] = val;
  } else if (i < 221184) {
    int j2 = i - 196608;
    int jj = j2 & 255, rc = j2 >> 8;
    int ci = rc & 31, r = rc >> 5;
    PI0[j2] = pack2(W_ih0[(r*256+jj)*64 + 2*ci], W_ih0[(r*256+jj)*64 + 2*ci + 1]);
  } else if (i < 319488) {
    int j3 = i - 221184;
    int tid = j3 & 1023, rc = j3 >> 10;
    int ci = rc & 31, r = rc >> 5;
    int kq = tid & 3, jj = tid >> 2;
    int col = 64*kq + 2*ci;
    PI1[j3] = pack2(W_ih1[(r*256+jj)*256 + col], W_ih1[(r*256+jj)*256 + col + 1]);
  }
}

// =================== GEMM0: gx0 = W_ih0 . x + biases (unchanged) ===================
__global__ __launch_bounds__(512) void gemm0_kernel(
    const float* __restrict__ x, const uint* __restrict__ PI0,
    const float* __restrict__ b_ih0, const float* __restrict__ b_hh0,
    ushortt* __restrict__ gx)
{
  const int blk = blockIdx.x;
  const int b = blk >> 4, t0 = (blk & 15) * 32;
  const int tid = threadIdx.x;
  const int j = tid & 255, th = tid >> 8;
  __shared__ uint xs[32*32];
  {
    float4 v = ((const float4*)x)[((size_t)b*TT + t0 + (tid>>4))*16 + (tid&15)];
    xs[(tid>>4)*32 + (tid&15)*2]     = pack2(v.x, v.y);
    xs[(tid>>4)*32 + (tid&15)*2 + 1] = pack2(v.z, v.w);
  }
  uint w[96];
  #pragma unroll
  for (int rc = 0; rc < 96; ++rc) w[rc] = PI0[rc*256 + j];
  const float br = b_ih0[j] + b_hh0[j];
  const float bz = b_ih0[256+j] + b_hh0[256+j];
  const float bn = b_ih0[512+j];
  __syncthreads();
  ushortt* gout = gx + ((size_t)b*TT + t0 + th*16)*768;
  #pragma unroll 1
  for (int tt = 0; tt < 16; ++tt) {
    const uint* xr = xs + (th*16 + tt)*32;
    float ar=0.f, az=0.f, an=0.f;
    #pragma unroll
    for (int c = 0; c < 32; ++c) {
      uint xv = xr[c];
      ar = dot2(w[c],    xv, ar);
      az = dot2(w[32+c], xv, az);
      an = dot2(w[64+c], xv, an);
    }
    gout[j]     = ff16(ar + br);
    gout[256+j] = ff16(az + bz);
    gout[512+j] = ff16(an + bn);
    gout += 768;
  }
}

// =================== GEMM1: gx1 = W_ih1 . h1 + biases (unchanged) ===================
__global__ __launch_bounds__(1024, 4) void gemm1_kernel(
    const uint* __restrict__ h1, const uint* __restrict__ PI1,
    const float* __restrict__ b_ih1, const float* __restrict__ b_hh1,
    ushortt* __restrict__ gx)
{
  const int blk = blockIdx.x;
  const int b = blk >> 5, t0 = (blk & 31) * 16;
  const int tid = threadIdx.x;
  const int kq = tid & 3, j = tid >> 2;
  __shared__ uint hsT[16*144];
  {
    uint2 v = ((const uint2*)(h1 + ((size_t)b*TT + t0)*128))[tid];
    int f = 2*tid, tp = f>>7, c = f&127, s = c>>2, e = c&3;
    *(uint2*)&hsT[tp*144 + (s + (s>>3))*4 + e] = v;
  }
  uint w[96];
  #pragma unroll
  for (int rc = 0; rc < 96; ++rc) w[rc] = PI1[rc*1024 + tid];
  const float br = b_ih1[j] + b_hh1[j];
  const float bz = b_ih1[256+j] + b_hh1[256+j];
  const float bn = b_ih1[512+j];
  __syncthreads();
  ushortt* gout = gx + ((size_t)b*TT + t0)*768;
  #pragma unroll 1
  for (int tt = 0; tt < 16; ++tt) {
    const uint4* hr = (const uint4*)&hsT[tt*144];
    float ar=0.f, az=0.f, an=0.f;
    #pragma unroll
    for (int i = 0; i < 8; ++i) {
      uint4 hv = hr[9*kq + i];
      ar = dot2(w[4*i],hv.x,ar);    ar = dot2(w[4*i+1],hv.y,ar);
      ar = dot2(w[4*i+2],hv.z,ar);  ar = dot2(w[4*i+3],hv.w,ar);
      az = dot2(w[32+4*i],hv.x,az); az = dot2(w[32+4*i+1],hv.y,az);
      az = dot2(w[32+4*i+2],hv.z,az); az = dot2(w[32+4*i+3],hv.w,az);
      an = dot2(w[64+4*i],hv.x,an); an = dot2(w[64+4*i+1],hv.y,an);
      an = dot2(w[64+4*i+2],hv.z,an); an = dot2(w[64+4*i+3],hv.w,an);
    }
    ar = red4(ar); az = red4(az); an = red4(an);
    if (kq == 0) {
      gout[j]     = ff16(ar + br);
      gout[256+j] = ff16(az + bz);
      gout[512+j] = ff16(an + bn);
    }
    gout += 768;
  }
}

// =================== REC: full-asm inner loop, weights pinned in v0-v95 ===================
// r24 = r23 (passing, 745 us/rec) + LDS-free reduction:
// r23's xor-4 exchange used ds_swizzle (LDS round-trip ~120-150cy + lgkmcnt(0)),
// on the serial reduce chain of ALL 16 barrier-lockstep waves, every step.
// Remap lane->(q,u): q = lane bits{0,1,3}, u = bits{2,4,5}+wave*8. The 8-lane
// reduce group then needs xor1 (quad_perm[1,0,3,2]), xor2 (quad_perm[2,3,0,1]),
// xor8 (row_ror:8) -- ALL DPP, no LDS. Weight image unchanged: thread loads
// entry old_tid = u*8+q. All (q,u)-derived indexing (gx j=2u+q, q==0 writers,
// lane^1 hx pack, h dbuf addrs) keeps the same formulas with remapped q,u.
// Register map: v0-v95 weights (loaded once), v96-v103 h ping-pong, v104-109
// accumulators, v110-v125 temps. Dbuf toggle in SGPR (r20 fix). gx 1-step
// prefetch (r23).
#define A(s) s "\n\t"
#define WL(a,b) A("global_load_dwordx4 v[" #a ":" #b "], v125, %[wi]") A("v_add_u32 v125, 0x4000, v125")
#define D6(w0,w1,w2,w3,w4,w5,hk) \
  A("v_dot2_f32_f16 v104, v" #w0 ", v" #hk ", v104") \
  A("v_dot2_f32_f16 v105, v" #w1 ", v" #hk ", v105") \
  A("v_dot2_f32_f16 v106, v" #w2 ", v" #hk ", v106") \
  A("v_dot2_f32_f16 v107, v" #w3 ", v" #hk ", v107") \
  A("v_dot2_f32_f16 v108, v" #w4 ", v" #hk ", v108") \
  A("v_dot2_f32_f16 v109, v" #w5 ", v" #hk ", v109")
#define RED_P1(a) \
  A("v_add_f32 v" #a ", v" #a ", v" #a " quad_perm:[1,0,3,2] row_mask:0xf bank_mask:0xf")
#define RED_P2(a) \
  A("v_add_f32 v" #a ", v" #a ", v" #a " quad_perm:[2,3,0,1] row_mask:0xf bank_mask:0xf")

#define REC_PROLOG \
  A("v_and_b32 v118, 3, %[tid]")            /* q lo = bits 0,1 */ \
  A("v_bfe_u32 v124, %[tid], 3, 1") \
  A("v_lshl_add_u32 v118, v124, 2, v118")   /* q = bit3*4 | bits01 */ \
  A("v_bfe_u32 v121, %[tid], 2, 1") \
  A("v_bfe_u32 v124, %[tid], 4, 2") \
  A("v_lshl_add_u32 v121, v124, 1, v121")   /* u lo = bits45*2 + bit2 */ \
  A("v_lshrrev_b32 v124, 6, %[tid]") \
  A("v_lshl_add_u32 v121, v124, 3, v121")   /* u = wave*8 + ulo */ \
  A("v_and_b32 v119, 1, v118")              /* odd */ \
  A("v_lshl_add_u32 v122, v121, 1, v118")   /* j = 2u+q */ \
  A("v_min_u32 v122, 0xff, v122")           /* clamp for q>=2 lanes */ \
  A("v_lshlrev_b32 v110, 1, v122")          /* gx byte voff = 2j */ \
  A("v_lshlrev_b32 v123, 2, v122") \
  A("global_load_dword v120, v123, %[bh] offset:2048")  /* bhn = b_hh[512+j] */ \
  A("global_load_ushort v111, v110, %[gx]")             /* gx prefetch t=0 */ \
  A("global_load_ushort v112, v110, %[gx] offset:512") \
  A("global_load_ushort v113, v110, %[gx] offset:1024") \
  A("v_mul_u32_u24 v115, 80, v118") \
  A("v_add_u32 v115, %[hb], v115")          /* rd addr (buf0): 80q */ \
  A("v_lshrrev_b32 v124, 4, v121") \
  A("v_lshl_add_u32 v124, v124, 2, v121")   /* u + 4*(u>>4) */ \
  A("v_lshlrev_b32 v124, 2, v124") \
  A("v_add_u32 v124, 0x280, v124") \
  A("v_add_u32 v116, %[hb], v124")          /* wr addr (buf1) */ \
  A("v_mov_b32 v114, 0")                    /* h_old */ \
  A("s_mov_b32 %[tog], 0x280")              /* dbuf toggle +/-640 (SGPR) */ \
  A("v_lshl_add_u32 v125, v121, 3, v118")   /* old_tid = u*8+q */ \
  A("v_lshlrev_b32 v125, 4, v125") \
  WL(0,3) WL(4,7) WL(8,11) WL(12,15) WL(16,19) WL(20,23) \
  WL(24,27) WL(28,31) WL(32,35) WL(36,39) WL(40,43) WL(44,47) \
  WL(48,51) WL(52,55) WL(56,59) WL(60,63) WL(64,67) WL(68,71) \
  WL(72,75) WL(76,79) WL(80,83) WL(84,87) WL(88,91) WL(92,95) \
  A("s_waitcnt vmcnt(0)") \
  A("s_mov_b32 %[cnt], 0")

#define REC_STEP_A \
  A("1:") \
  A("ds_read_b128 v[96:99], v115") \
  A("ds_read_b128 v[100:103], v115 offset:16") \
  A("v_mov_b32 v104, 0") A("v_mov_b32 v105, 0") A("v_mov_b32 v106, 0") \
  A("v_mov_b32 v107, 0") A("v_mov_b32 v108, 0") A("v_mov_b32 v109, 0") \
  A("s_waitcnt lgkmcnt(1)") \
  D6(0,16,32,48,64,80,96) D6(1,17,33,49,65,81,97) \
  D6(2,18,34,50,66,82,98) D6(3,19,35,51,67,83,99) \
  A("ds_read_b128 v[96:99], v115 offset:32") \
  A("s_waitcnt lgkmcnt(1)") \
  D6(4,20,36,52,68,84,100) D6(5,21,37,53,69,85,101) \
  D6(6,22,38,54,70,86,102) D6(7,23,39,55,71,87,103) \
  A("ds_read_b128 v[100:103], v115 offset:48") \
  A("s_waitcnt lgkmcnt(1)") \
  D6(8,24,40,56,72,88,96) D6(9,25,41,57,73,89,97) \
  D6(10,26,42,58,74,90,98) D6(11,27,43,59,75,91,99) \
  A("s_waitcnt lgkmcnt(0)") \
  D6(12,28,44,60,76,92,100) D6(13,29,45,61,77,93,101) \
  D6(14,30,46,62,78,94,102) D6(15,31,47,63,79,95,103) \
  RED_P1(104) RED_P1(105) RED_P1(106) RED_P1(107) RED_P1(108) RED_P1(109) \
  RED_P2(104) RED_P2(105) RED_P2(106) RED_P2(107) RED_P2(108) RED_P2(109) \
  A("v_mov_b32 v96, v104 row_ror:8 row_mask:0xf bank_mask:0xf") \
  A("v_mov_b32 v97, v105 row_ror:8 row_mask:0xf bank_mask:0xf") \
  A("v_mov_b32 v98, v106 row_ror:8 row_mask:0xf bank_mask:0xf") \
  A("v_mov_b32 v99, v107 row_ror:8 row_mask:0xf bank_mask:0xf") \
  A("v_mov_b32 v100, v108 row_ror:8 row_mask:0xf bank_mask:0xf") \
  A("v_mov_b32 v101, v109 row_ror:8 row_mask:0xf bank_mask:0xf") \
  A("v_add_f32 v104, v104, v96") A("v_add_f32 v105, v105, v97") \
  A("v_add_f32 v106, v106, v98") A("v_add_f32 v107, v107, v99") \
  A("v_add_f32 v108, v108, v100") A("v_add_f32 v109, v109, v101") \
  A("v_cmp_eq_u32 vcc, 1, v119") \
  A("v_cndmask_b32 v121, v104, v105, vcc")  /* Sr */ \
  A("v_cndmask_b32 v122, v106, v107, vcc")  /* Sz */ \
  A("v_cndmask_b32 v123, v108, v109, vcc")  /* Sn */ \
  A("s_waitcnt vmcnt(0)") \
  A("v_cvt_f32_f16 v124, v111") \
  A("v_add_f32 v121, v121, v124") \
  A("v_mul_f32 v121, 0xbfb8aa3b, v121") \
  A("v_exp_f32 v121, v121") \
  A("s_nop 1") \
  A("v_add_f32 v121, 1.0, v121") \
  A("v_rcp_f32 v121, v121")                 /* r */ \
  A("v_cvt_f32_f16 v124, v112") \
  A("v_add_f32 v122, v122, v124") \
  A("v_mul_f32 v122, 0xbfb8aa3b, v122") \
  A("v_exp_f32 v122, v122") \
  A("s_nop 1") \
  A("v_add_f32 v122, 1.0, v122") \
  A("v_rcp_f32 v122, v122")                 /* z */ \
  A("v_add_f32 v123, v123, v120") \
  A("v_cvt_f32_f16 v124, v113") \
  A("s_nop 1") \
  A("v_fma_f32 v123, v121, v123, v124")     /* pre-n */ \
  A("s_cmp_lt_u32 %[cnt], 511")             /* gx prefetch for t+1 (skip at t=511) */ \
  A("s_cbranch_scc0 2f") \
  A("v_add_u32 v110, 0x600, v110") \
  A("global_load_ushort v111, v110, %[gx]") \
  A("global_load_ushort v112, v110, %[gx] offset:512") \
  A("global_load_ushort v113, v110, %[gx] offset:1024") \
  A("2:") \
  A("v_max_f32 v123, 0xc1700000, v123") \
  A("v_min_f32 v123, 0x41700000, v123") \
  A("v_mul_f32 v123, 0x4038aa3b, v123") \
  A("v_exp_f32 v123, v123") \
  A("s_nop 1") \
  A("v_add_f32 v124, 1.0, v123") \
  A("v_rcp_f32 v124, v124") \
  A("v_add_f32 v123, -1.0, v123") \
  A("s_nop 1") \
  A("v_mul_f32 v123, v123, v124")           /* n */ \
  A("v_sub_f32 v124, v114, v123") \
  A("v_fma_f32 v114, v122, v124, v123")     /* h_old = hn */ \
  A("v_cvt_f16_f32 v125, v114") \
  A("v_and_b32 v125, 0xffff, v125") \
  A("v_mov_b32 v124, v114 quad_perm:[1,0,3,2] row_mask:0xf bank_mask:0xf") \
  A("v_cvt_f16_f32 v124, v124") \
  A("v_lshlrev_b32 v124, 16, v124") \
  A("v_or_b32 v125, v124, v125")            /* hv2 = pack2(hn_even, hn_odd) */ \
  A("v_cmp_eq_u32 vcc, 0, v118") \
  A("s_and_saveexec_b64 %[sx], vcc") \
  A("ds_write_b32 v116, v125")

#define REC_STEP_B \
  A("s_mov_b64 exec, -1") \
  A("v_add_u32 v115, %[tog], v115")         /* rd buf toggle (+/-640) */ \
  A("v_subrev_u32 v116, %[tog], v116")      /* wr buf toggle (-/+640) */ \
  A("s_sub_u32 %[tog], 0, %[tog]") \
  A("s_waitcnt lgkmcnt(0)") \
  A("s_barrier") \
  A("s_add_u32 %[cnt], %[cnt], 1") \
  A("s_cmp_lt_u32 %[cnt], 512") \
  A("s_cbranch_scc1 1b")

#define REC_CLOBBERS \
  "memory","vcc","scc", \
  "v0","v1","v2","v3","v4","v5","v6","v7","v8","v9","v10","v11","v12","v13","v14","v15", \
  "v16","v17","v18","v19","v20","v21","v22","v23","v24","v25","v26","v27","v28","v29","v30","v31", \
  "v32","v33","v34","v35","v36","v37","v38","v39","v40","v41","v42","v43","v44","v45","v46","v47", \
  "v48","v49","v50","v51","v52","v53","v54","v55","v56","v57","v58","v59","v60","v61","v62","v63", \
  "v64","v65","v66","v67","v68","v69","v70","v71","v72","v73","v74","v75","v76","v77","v78","v79", \
  "v80","v81","v82","v83","v84","v85","v86","v87","v88","v89","v90","v91","v92","v93","v94","v95", \
  "v96","v97","v98","v99","v100","v101","v102","v103","v104","v105","v106","v107","v108","v109", \
  "v110","v111","v112","v113","v114","v115","v116","v117","v118","v119","v120","v121","v122","v123","v124","v125"

template<bool IS_L0>
__global__ __launch_bounds__(1024) void rec_kernel(
    const uint* __restrict__ Wimg, const ushortt* __restrict__ GX,
    const float* __restrict__ b_hh,
    uint* __restrict__ h1, float* __restrict__ h2o)
{
  __shared__ __align__(16) uint hb[320];    // 2 x 160-uint padded h dbuf (r7 layout)
  const uint tid = threadIdx.x;
  if (tid < 320) hb[tid] = 0;
  __syncthreads();
  const uint hbaddr = (uint)(uintptr_t)(&hb[0]);
  const int b = blockIdx.x;
  const ushortt* gxp = GX + (size_t)b*TT*768;
  uint cnt, tog; unsigned long long sx;
  if constexpr (IS_L0) {
    uint* h1p = h1 + (size_t)b*TT*128;
    asm volatile(
      REC_PROLOG
      A("v_lshlrev_b32 v117, 2, v121")      /* h1 voff = u*4 */
      REC_STEP_A
      A("global_store_dword v117, v125, %[h1]")
      A("v_add_u32 v117, 0x200, v117")
      REC_STEP_B
      : [cnt]"=&s"(cnt), [sx]"=&s"(sx), [tog]"=&s"(tog)
      : [tid]"v"(tid), [hb]"v"(hbaddr), [gx]"s"(gxp), [wi]"s"(Wimg),
        [bh]"s"(b_hh), [h1]"s"(h1p)
      : REC_CLOBBERS);
  } else {
    float* hop = h2o + (size_t)b*256;
    asm volatile(
      REC_PROLOG
      A("v_lshlrev_b32 v117, 2, v122")      /* h2o voff = j*4 */
      REC_STEP_A
      REC_STEP_B
      A("v_cmp_gt_u32 vcc, 2, v118")        /* q < 2 */
      A("s_and_saveexec_b64 %[sx], vcc")
      A("global_store_dword v117, v114, %[ho]")
      A("s_mov_b64 exec, -1")
      : [cnt]"=&s"(cnt), [sx]"=&s"(sx), [tog]"=&s"(tog)
      : [tid]"v"(tid), [hb]"v"(hbaddr), [gx]"s"(gxp), [wi]"s"(Wimg),
        [bh]"s"(b_hh), [ho]"s"(hop)
      : REC_CLOBBERS);
  }
}

// =================== MLP head (unchanged) ===================
__global__ __launch_bounds__(128) void mlp_kernel(
    const float* __restrict__ h2, const float* __restrict__ W1,
    const float* __restrict__ b1, const float* __restrict__ W2,
    const float* __restrict__ b2, float* __restrict__ out)
{
  __shared__ float hls[256];
  __shared__ float red[128];
  const int b = blockIdx.x, tid = threadIdx.x;
  if (tid < 64) ((float4*)hls)[tid] = ((const float4*)(h2 + (size_t)b*256))[tid];
  __syncthreads();
  float acc = b1[tid];
  const float4* w4 = (const float4*)(W1 + (size_t)tid*256);
  const float4* h4 = (const float4*)hls;
  #pragma unroll 8
  for (int k = 0; k < 64; ++k) {
    float4 w = w4[k]; float4 h = h4[k];
    acc = fmaf(w.x,h.x,acc); acc = fmaf(w.y,h.y,acc);
    acc = fmaf(w.z,h.z,acc); acc = fmaf(w.w,h.w,acc);
  }
  red[tid] = fmaxf(acc, 0.0f) * W2[tid];
  __syncthreads();
  for (int s = 64; s > 0; s >>= 1) {
    if (tid < s) red[tid] += red[tid + s];
    __syncthreads();
  }
  if (tid == 0) out[b] = red[0] + b2[0];
}

extern "C" void kernel_launch(void* const* d_in, const int* in_sizes, int n_in,
                              void* d_out, int out_size, void* d_ws, size_t ws_size,
                              hipStream_t stream)
{
  const float* x     = (const float*)d_in[0];
  const float* W_ih0 = (const float*)d_in[1];
  const float* W_hh0 = (const float*)d_in[2];
  const float* b_ih0 = (const float*)d_in[3];
  const float* b_hh0 = (const float*)d_in[4];
  const float* W_ih1 = (const float*)d_in[5];
  const float* W_hh1 = (const float*)d_in[6];
  const float* b_ih1 = (const float*)d_in[7];
  const float* b_hh1 = (const float*)d_in[8];
  const float* W1    = (const float*)d_in[9];
  const float* b1    = (const float*)d_in[10];
  const float* W2    = (const float*)d_in[11];
  const float* b2    = (const float*)d_in[12];

  char* ws = (char*)d_ws;
  uint*    W0i  = (uint*)(ws + OFF_W0);
  uint*    W1i  = (uint*)(ws + OFF_W1);
  uint*    PI0  = (uint*)(ws + OFF_PI0);
  uint*    PI1  = (uint*)(ws + OFF_PI1);
  float*   H2O  = (float*)(ws + OFF_H2O);
  uint*    H1   = (uint*)(ws + OFF_H1);
  ushortt* GX   = (ushortt*)(ws + OFF_GX);

  prep_kernel<<<1248, 256, 0, stream>>>(W_ih0, W_hh0, W_ih1, W_hh1,
                                        W0i, W1i, PI0, PI1);
  gemm0_kernel<<<2048, 512, 0, stream>>>(x, PI0, b_ih0, b_hh0, GX);
  rec_kernel<true><<<BB, 1024, 0, stream>>>(W0i, GX, b_hh0, H1, nullptr);
  gemm1_kernel<<<4096, 1024, 0, stream>>>(H1, PI1, b_ih1, b_hh1, GX);
  rec_kernel<false><<<BB, 1024, 0, stream>>>(W1i, GX, b_hh1, nullptr, H2O);
  mlp_kernel<<<BB, 128, 0, stream>>>(H2O, W1, b1, W2, b2, (float*)d_out);
}

// Round 15
// 1779.747 us; speedup vs baseline: 1.0395x; 1.0113x over previous
//
#include <hip/hip_runtime.h>
#include <cstdint>
#include <cstddef>

typedef _Float16 h2_t __attribute__((ext_vector_type(2)));
typedef unsigned int uint;
typedef unsigned short ushortt;

#define BB 128
#define TT 512

// ---- ws layout (bytes) ----
#define OFF_W0   0u           // 393216  (layer0 W_hh image, 24 chunks x 1024 quads)
#define OFF_W1   393216u      // 393216  (layer1)
#define OFF_PI0  786432u      // 98304
#define OFF_PI1  884736u      // 393216
#define OFF_H2O  1277952u     // 131072
#define OFF_H1   1409024u     // 33554432
#define OFF_GX   34963456u    // 100663296 (end ~135.6 MB)

__device__ __forceinline__ uint pack2(float a, float b){
  h2_t h; h.x = (_Float16)a; h.y = (_Float16)b;
  return __builtin_bit_cast(uint, h);
}
__device__ __forceinline__ float f16f(ushortt s){
  return (float)__builtin_bit_cast(_Float16, s);
}
__device__ __forceinline__ ushortt ff16(float f){
  return __builtin_bit_cast(ushortt, (_Float16)f);
}
__device__ __forceinline__ float dot2(uint w, uint h, float acc){
  return __builtin_amdgcn_fdot2(__builtin_bit_cast(h2_t, w),
                                __builtin_bit_cast(h2_t, h), acc, false);
}
template<int CTRL>
__device__ __forceinline__ float dpp_addf(float x){
  int p = __builtin_amdgcn_update_dpp(0, __float_as_int(x), CTRL, 0xF, 0xF, true);
  return x + __int_as_float(p);
}
// sum over 4-lane quads, result in all 4 lanes (verified r4-r8)
__device__ __forceinline__ float red4(float x){
  x = dpp_addf<0xB1>(x); x = dpp_addf<0x4E>(x);
  return x;
}

// =================== prep: pack fp32 weights -> f16 images ===================
// W_hh image (r5/r7-verified REC org, all 24 chunks in one image):
// dword j: e=j&3, tid=(j>>2)&1023, c=(j>>2)>>10. Thread (q=tid&7, u=tid>>3),
// chunk c=r*4+k4, r=g*2+s: row=g*256+2u+s, col=32q+8k4+2e (+1).
// r24: REC threads remap lane->(q,u) (q=bits013, u=bits245+wave) and load the
// image entry old_tid = u*8+q -- image layout itself unchanged.
__global__ void prep_kernel(const float* __restrict__ W_ih0, const float* __restrict__ W_hh0,
                            const float* __restrict__ W_ih1, const float* __restrict__ W_hh1,
                            uint* __restrict__ W0, uint* __restrict__ W1,
                            uint* __restrict__ PI0, uint* __restrict__ PI1)
{
  int i = blockIdx.x*256 + threadIdx.x;
  if (i < 196608) {
    const int layer = (i >= 98304) ? 1 : 0;
    const float* W = layer ? W_hh1 : W_hh0;
    int j = layer ? (i - 98304) : i;
    int e = j&3, r2 = j>>2;
    int tid = r2 & 1023, c = r2 >> 10;
    int q = tid&7, u = tid>>3, k4 = c&3, r = c>>2;
    int g = r>>1, s = r&1;
    int row = g*256 + 2*u + s, col = 32*q + 8*k4 + 2*e;
    uint val = pack2(W[row*256+col], W[row*256+col+1]);
    (layer ? W1 : W0)[j] = val;
  } else if (i < 221184) {
    int j2 = i - 196608;
    int jj = j2 & 255, rc = j2 >> 8;
    int ci = rc & 31, r = rc >> 5;
    PI0[j2] = pack2(W_ih0[(r*256+jj)*64 + 2*ci], W_ih0[(r*256+jj)*64 + 2*ci + 1]);
  } else if (i < 319488) {
    int j3 = i - 221184;
    int tid = j3 & 1023, rc = j3 >> 10;
    int ci = rc & 31, r = rc >> 5;
    int kq = tid & 3, jj = tid >> 2;
    int col = 64*kq + 2*ci;
    PI1[j3] = pack2(W_ih1[(r*256+jj)*256 + col], W_ih1[(r*256+jj)*256 + col + 1]);
  }
}

// =================== GEMM0: gx0 = W_ih0 . x + biases (unchanged) ===================
__global__ __launch_bounds__(512) void gemm0_kernel(
    const float* __restrict__ x, const uint* __restrict__ PI0,
    const float* __restrict__ b_ih0, const float* __restrict__ b_hh0,
    ushortt* __restrict__ gx)
{
  const int blk = blockIdx.x;
  const int b = blk >> 4, t0 = (blk & 15) * 32;
  const int tid = threadIdx.x;
  const int j = tid & 255, th = tid >> 8;
  __shared__ uint xs[32*32];
  {
    float4 v = ((const float4*)x)[((size_t)b*TT + t0 + (tid>>4))*16 + (tid&15)];
    xs[(tid>>4)*32 + (tid&15)*2]     = pack2(v.x, v.y);
    xs[(tid>>4)*32 + (tid&15)*2 + 1] = pack2(v.z, v.w);
  }
  uint w[96];
  #pragma unroll
  for (int rc = 0; rc < 96; ++rc) w[rc] = PI0[rc*256 + j];
  const float br = b_ih0[j] + b_hh0[j];
  const float bz = b_ih0[256+j] + b_hh0[256+j];
  const float bn = b_ih0[512+j];
  __syncthreads();
  ushortt* gout = gx + ((size_t)b*TT + t0 + th*16)*768;
  #pragma unroll 1
  for (int tt = 0; tt < 16; ++tt) {
    const uint* xr = xs + (th*16 + tt)*32;
    float ar=0.f, az=0.f, an=0.f;
    #pragma unroll
    for (int c = 0; c < 32; ++c) {
      uint xv = xr[c];
      ar = dot2(w[c],    xv, ar);
      az = dot2(w[32+c], xv, az);
      an = dot2(w[64+c], xv, an);
    }
    gout[j]     = ff16(ar + br);
    gout[256+j] = ff16(az + bz);
    gout[512+j] = ff16(an + bn);
    gout += 768;
  }
}

// =================== GEMM1: gx1 = W_ih1 . h1 + biases (unchanged) ===================
__global__ __launch_bounds__(1024, 4) void gemm1_kernel(
    const uint* __restrict__ h1, const uint* __restrict__ PI1,
    const float* __restrict__ b_ih1, const float* __restrict__ b_hh1,
    ushortt* __restrict__ gx)
{
  const int blk = blockIdx.x;
  const int b = blk >> 5, t0 = (blk & 31) * 16;
  const int tid = threadIdx.x;
  const int kq = tid & 3, j = tid >> 2;
  __shared__ uint hsT[16*144];
  {
    uint2 v = ((const uint2*)(h1 + ((size_t)b*TT + t0)*128))[tid];
    int f = 2*tid, tp = f>>7, c = f&127, s = c>>2, e = c&3;
    *(uint2*)&hsT[tp*144 + (s + (s>>3))*4 + e] = v;
  }
  uint w[96];
  #pragma unroll
  for (int rc = 0; rc < 96; ++rc) w[rc] = PI1[rc*1024 + tid];
  const float br = b_ih1[j] + b_hh1[j];
  const float bz = b_ih1[256+j] + b_hh1[256+j];
  const float bn = b_ih1[512+j];
  __syncthreads();
  ushortt* gout = gx + ((size_t)b*TT + t0)*768;
  #pragma unroll 1
  for (int tt = 0; tt < 16; ++tt) {
    const uint4* hr = (const uint4*)&hsT[tt*144];
    float ar=0.f, az=0.f, an=0.f;
    #pragma unroll
    for (int i = 0; i < 8; ++i) {
      uint4 hv = hr[9*kq + i];
      ar = dot2(w[4*i],hv.x,ar);    ar = dot2(w[4*i+1],hv.y,ar);
      ar = dot2(w[4*i+2],hv.z,ar);  ar = dot2(w[4*i+3],hv.w,ar);
      az = dot2(w[32+4*i],hv.x,az); az = dot2(w[32+4*i+1],hv.y,az);
      az = dot2(w[32+4*i+2],hv.z,az); az = dot2(w[32+4*i+3],hv.w,az);
      an = dot2(w[64+4*i],hv.x,an); an = dot2(w[64+4*i+1],hv.y,an);
      an = dot2(w[64+4*i+2],hv.z,an); an = dot2(w[64+4*i+3],hv.w,an);
    }
    ar = red4(ar); az = red4(az); an = red4(an);
    if (kq == 0) {
      gout[j]     = ff16(ar + br);
      gout[256+j] = ff16(az + bz);
      gout[512+j] = ff16(an + bn);
    }
    gout += 768;
  }
}

// =================== REC: full-asm inner loop, weights pinned in v0-v95 ===================
// r25 = r24 (passing, 725 us/rec) + interleaved gate chains:
// r24's gate region was ~36 serially-dependent slots (r chain, then z chain,
// then n chain, plus 5 defensive s_nops) -- executed in barrier-lockstep by all
// 4 waves/SIMD, so nothing fills the trans-op latency. r25 interleaves the
// independent r/z chains pairwise (each exp/rcp covered by its sibling), folds
// Sn+bhn early, converts all 3 gx values up front into v96-98 (free after the
// reduce), and drops the s_nops (interleave provides the gaps; VALU-after-trans
// same-reg dependencies are HW-interlocked -- r16-18's failures were the XOR
// address bug, not hazards). Same ops, same per-value dependency order ->
// bit-identical numerics. Serial region ~36 -> ~24 slots.
// Register map: v0-v95 weights (loaded once), v96-v103 h ping-pong / temps,
// v104-109 accumulators, v110-v125 temps. Dbuf toggle in SGPR (r20). gx 1-step
// prefetch (r23). DPP-only reduction via lane remap (r24).
#define A(s) s "\n\t"
#define WL(a,b) A("global_load_dwordx4 v[" #a ":" #b "], v125, %[wi]") A("v_add_u32 v125, 0x4000, v125")
#define D6(w0,w1,w2,w3,w4,w5,hk) \
  A("v_dot2_f32_f16 v104, v" #w0 ", v" #hk ", v104") \
  A("v_dot2_f32_f16 v105, v" #w1 ", v" #hk ", v105") \
  A("v_dot2_f32_f16 v106, v" #w2 ", v" #hk ", v106") \
  A("v_dot2_f32_f16 v107, v" #w3 ", v" #hk ", v107") \
  A("v_dot2_f32_f16 v108, v" #w4 ", v" #hk ", v108") \
  A("v_dot2_f32_f16 v109, v" #w5 ", v" #hk ", v109")
#define RED_P1(a) \
  A("v_add_f32 v" #a ", v" #a ", v" #a " quad_perm:[1,0,3,2] row_mask:0xf bank_mask:0xf")
#define RED_P2(a) \
  A("v_add_f32 v" #a ", v" #a ", v" #a " quad_perm:[2,3,0,1] row_mask:0xf bank_mask:0xf")

#define REC_PROLOG \
  A("v_and_b32 v118, 3, %[tid]")            /* q lo = bits 0,1 */ \
  A("v_bfe_u32 v124, %[tid], 3, 1") \
  A("v_lshl_add_u32 v118, v124, 2, v118")   /* q = bit3*4 | bits01 */ \
  A("v_bfe_u32 v121, %[tid], 2, 1") \
  A("v_bfe_u32 v124, %[tid], 4, 2") \
  A("v_lshl_add_u32 v121, v124, 1, v121")   /* u lo = bits45*2 + bit2 */ \
  A("v_lshrrev_b32 v124, 6, %[tid]") \
  A("v_lshl_add_u32 v121, v124, 3, v121")   /* u = wave*8 + ulo */ \
  A("v_and_b32 v119, 1, v118")              /* odd */ \
  A("v_lshl_add_u32 v122, v121, 1, v118")   /* j = 2u+q */ \
  A("v_min_u32 v122, 0xff, v122")           /* clamp for q>=2 lanes */ \
  A("v_lshlrev_b32 v110, 1, v122")          /* gx byte voff = 2j */ \
  A("v_lshlrev_b32 v123, 2, v122") \
  A("global_load_dword v120, v123, %[bh] offset:2048")  /* bhn = b_hh[512+j] */ \
  A("global_load_ushort v111, v110, %[gx]")             /* gx prefetch t=0 */ \
  A("global_load_ushort v112, v110, %[gx] offset:512") \
  A("global_load_ushort v113, v110, %[gx] offset:1024") \
  A("v_mul_u32_u24 v115, 80, v118") \
  A("v_add_u32 v115, %[hb], v115")          /* rd addr (buf0): 80q */ \
  A("v_lshrrev_b32 v124, 4, v121") \
  A("v_lshl_add_u32 v124, v124, 2, v121")   /* u + 4*(u>>4) */ \
  A("v_lshlrev_b32 v124, 2, v124") \
  A("v_add_u32 v124, 0x280, v124") \
  A("v_add_u32 v116, %[hb], v124")          /* wr addr (buf1) */ \
  A("v_mov_b32 v114, 0")                    /* h_old */ \
  A("s_mov_b32 %[tog], 0x280")              /* dbuf toggle +/-640 (SGPR) */ \
  A("v_lshl_add_u32 v125, v121, 3, v118")   /* old_tid = u*8+q */ \
  A("v_lshlrev_b32 v125, 4, v125") \
  WL(0,3) WL(4,7) WL(8,11) WL(12,15) WL(16,19) WL(20,23) \
  WL(24,27) WL(28,31) WL(32,35) WL(36,39) WL(40,43) WL(44,47) \
  WL(48,51) WL(52,55) WL(56,59) WL(60,63) WL(64,67) WL(68,71) \
  WL(72,75) WL(76,79) WL(80,83) WL(84,87) WL(88,91) WL(92,95) \
  A("s_waitcnt vmcnt(0)") \
  A("s_mov_b32 %[cnt], 0")

#define REC_STEP_A \
  A("1:") \
  A("ds_read_b128 v[96:99], v115") \
  A("ds_read_b128 v[100:103], v115 offset:16") \
  A("v_mov_b32 v104, 0") A("v_mov_b32 v105, 0") A("v_mov_b32 v106, 0") \
  A("v_mov_b32 v107, 0") A("v_mov_b32 v108, 0") A("v_mov_b32 v109, 0") \
  A("s_waitcnt lgkmcnt(1)") \
  D6(0,16,32,48,64,80,96) D6(1,17,33,49,65,81,97) \
  D6(2,18,34,50,66,82,98) D6(3,19,35,51,67,83,99) \
  A("ds_read_b128 v[96:99], v115 offset:32") \
  A("s_waitcnt lgkmcnt(1)") \
  D6(4,20,36,52,68,84,100) D6(5,21,37,53,69,85,101) \
  D6(6,22,38,54,70,86,102) D6(7,23,39,55,71,87,103) \
  A("ds_read_b128 v[100:103], v115 offset:48") \
  A("s_waitcnt lgkmcnt(1)") \
  D6(8,24,40,56,72,88,96) D6(9,25,41,57,73,89,97) \
  D6(10,26,42,58,74,90,98) D6(11,27,43,59,75,91,99) \
  A("s_waitcnt lgkmcnt(0)") \
  D6(12,28,44,60,76,92,100) D6(13,29,45,61,77,93,101) \
  D6(14,30,46,62,78,94,102) D6(15,31,47,63,79,95,103) \
  RED_P1(104) RED_P1(105) RED_P1(106) RED_P1(107) RED_P1(108) RED_P1(109) \
  RED_P2(104) RED_P2(105) RED_P2(106) RED_P2(107) RED_P2(108) RED_P2(109) \
  A("v_mov_b32 v96, v104 row_ror:8 row_mask:0xf bank_mask:0xf") \
  A("v_mov_b32 v97, v105 row_ror:8 row_mask:0xf bank_mask:0xf") \
  A("v_mov_b32 v98, v106 row_ror:8 row_mask:0xf bank_mask:0xf") \
  A("v_mov_b32 v99, v107 row_ror:8 row_mask:0xf bank_mask:0xf") \
  A("v_mov_b32 v100, v108 row_ror:8 row_mask:0xf bank_mask:0xf") \
  A("v_mov_b32 v101, v109 row_ror:8 row_mask:0xf bank_mask:0xf") \
  A("v_add_f32 v104, v104, v96") A("v_add_f32 v105, v105, v97") \
  A("v_add_f32 v106, v106, v98") A("v_add_f32 v107, v107, v99") \
  A("v_add_f32 v108, v108, v100") A("v_add_f32 v109, v109, v101") \
  A("v_cmp_eq_u32 vcc, 1, v119") \
  A("v_cndmask_b32 v121, v104, v105, vcc")  /* Sr */ \
  A("v_cndmask_b32 v122, v106, v107, vcc")  /* Sz */ \
  A("v_cndmask_b32 v123, v108, v109, vcc")  /* Sn */ \
  A("s_waitcnt vmcnt(0)") \
  A("v_cvt_f32_f16 v96, v111")              /* gr */ \
  A("v_cvt_f32_f16 v97, v112")              /* gz */ \
  A("v_cvt_f32_f16 v98, v113")              /* gn */ \
  A("v_add_f32 v121, v121, v96") \
  A("v_add_f32 v122, v122, v97") \
  A("v_add_f32 v123, v123, v120")           /* Sn + bhn (early, indep of r) */ \
  A("v_mul_f32 v121, 0xbfb8aa3b, v121") \
  A("v_mul_f32 v122, 0xbfb8aa3b, v122") \
  A("v_exp_f32 v121, v121") \
  A("v_exp_f32 v122, v122") \
  A("v_add_f32 v121, 1.0, v121") \
  A("v_add_f32 v122, 1.0, v122") \
  A("v_rcp_f32 v121, v121")                 /* r */ \
  A("v_rcp_f32 v122, v122")                 /* z */ \
  A("v_fma_f32 v123, v121, v123, v98")      /* pre-n = gn + r*(Sn+bhn) */ \
  A("v_max_f32 v123, 0xc1700000, v123") \
  A("v_min_f32 v123, 0x41700000, v123") \
  A("v_mul_f32 v123, 0x4038aa3b, v123") \
  A("v_exp_f32 v123, v123") \
  A("s_cmp_lt_u32 %[cnt], 511")             /* gx prefetch for t+1 (fills exp latency) */ \
  A("s_cbranch_scc0 2f") \
  A("v_add_u32 v110, 0x600, v110") \
  A("global_load_ushort v111, v110, %[gx]") \
  A("global_load_ushort v112, v110, %[gx] offset:512") \
  A("global_load_ushort v113, v110, %[gx] offset:1024") \
  A("2:") \
  A("v_add_f32 v124, 1.0, v123") \
  A("v_rcp_f32 v124, v124") \
  A("v_add_f32 v123, -1.0, v123") \
  A("v_mul_f32 v123, v123, v124")           /* n */ \
  A("v_sub_f32 v124, v114, v123") \
  A("v_fma_f32 v114, v122, v124, v123")     /* h_old = hn */ \
  A("v_cvt_f16_f32 v125, v114") \
  A("v_and_b32 v125, 0xffff, v125") \
  A("v_mov_b32 v124, v114 quad_perm:[1,0,3,2] row_mask:0xf bank_mask:0xf") \
  A("v_cvt_f16_f32 v124, v124") \
  A("v_lshlrev_b32 v124, 16, v124") \
  A("v_or_b32 v125, v124, v125")            /* hv2 = pack2(hn_even, hn_odd) */ \
  A("v_cmp_eq_u32 vcc, 0, v118") \
  A("s_and_saveexec_b64 %[sx], vcc") \
  A("ds_write_b32 v116, v125")

#define REC_STEP_B \
  A("s_mov_b64 exec, -1") \
  A("v_add_u32 v115, %[tog], v115")         /* rd buf toggle (+/-640) */ \
  A("v_subrev_u32 v116, %[tog], v116")      /* wr buf toggle (-/+640) */ \
  A("s_sub_u32 %[tog], 0, %[tog]") \
  A("s_waitcnt lgkmcnt(0)") \
  A("s_barrier") \
  A("s_add_u32 %[cnt], %[cnt], 1") \
  A("s_cmp_lt_u32 %[cnt], 512") \
  A("s_cbranch_scc1 1b")

#define REC_CLOBBERS \
  "memory","vcc","scc", \
  "v0","v1","v2","v3","v4","v5","v6","v7","v8","v9","v10","v11","v12","v13","v14","v15", \
  "v16","v17","v18","v19","v20","v21","v22","v23","v24","v25","v26","v27","v28","v29","v30","v31", \
  "v32","v33","v34","v35","v36","v37","v38","v39","v40","v41","v42","v43","v44","v45","v46","v47", \
  "v48","v49","v50","v51","v52","v53","v54","v55","v56","v57","v58","v59","v60","v61","v62","v63", \
  "v64","v65","v66","v67","v68","v69","v70","v71","v72","v73","v74","v75","v76","v77","v78","v79", \
  "v80","v81","v82","v83","v84","v85","v86","v87","v88","v89","v90","v91","v92","v93","v94","v95", \
  "v96","v97","v98","v99","v100","v101","v102","v103","v104","v105","v106","v107","v108","v109", \
  "v110","v111","v112","v113","v114","v115","v116","v117","v118","v119","v120","v121","v122","v123","v124","v125"

template<bool IS_L0>
__global__ __launch_bounds__(1024) void rec_kernel(
    const uint* __restrict__ Wimg, const ushortt* __restrict__ GX,
    const float* __restrict__ b_hh,
    uint* __restrict__ h1, float* __restrict__ h2o)
{
  __shared__ __align__(16) uint hb[320];    // 2 x 160-uint padded h dbuf (r7 layout)
  const uint tid = threadIdx.x;
  if (tid < 320) hb[tid] = 0;
  __syncthreads();
  const uint hbaddr = (uint)(uintptr_t)(&hb[0]);
  const int b = blockIdx.x;
  const ushortt* gxp = GX + (size_t)b*TT*768;
  uint cnt, tog; unsigned long long sx;
  if constexpr (IS_L0) {
    uint* h1p = h1 + (size_t)b*TT*128;
    asm volatile(
      REC_PROLOG
      A("v_lshlrev_b32 v117, 2, v121")      /* h1 voff = u*4 */
      REC_STEP_A
      A("global_store_dword v117, v125, %[h1]")
      A("v_add_u32 v117, 0x200, v117")
      REC_STEP_B
      : [cnt]"=&s"(cnt), [sx]"=&s"(sx), [tog]"=&s"(tog)
      : [tid]"v"(tid), [hb]"v"(hbaddr), [gx]"s"(gxp), [wi]"s"(Wimg),
        [bh]"s"(b_hh), [h1]"s"(h1p)
      : REC_CLOBBERS);
  } else {
    float* hop = h2o + (size_t)b*256;
    asm volatile(
      REC_PROLOG
      A("v_lshlrev_b32 v117, 2, v122")      /* h2o voff = j*4 */
      REC_STEP_A
      REC_STEP_B
      A("v_cmp_gt_u32 vcc, 2, v118")        /* q < 2 */
      A("s_and_saveexec_b64 %[sx], vcc")
      A("global_store_dword v117, v114, %[ho]")
      A("s_mov_b64 exec, -1")
      : [cnt]"=&s"(cnt), [sx]"=&s"(sx), [tog]"=&s"(tog)
      : [tid]"v"(tid), [hb]"v"(hbaddr), [gx]"s"(gxp), [wi]"s"(Wimg),
        [bh]"s"(b_hh), [ho]"s"(hop)
      : REC_CLOBBERS);
  }
}

// =================== MLP head (unchanged) ===================
__global__ __launch_bounds__(128) void mlp_kernel(
    const float* __restrict__ h2, const float* __restrict__ W1,
    const float* __restrict__ b1, const float* __restrict__ W2,
    const float* __restrict__ b2, float* __restrict__ out)
{
  __shared__ float hls[256];
  __shared__ float red[128];
  const int b = blockIdx.x, tid = threadIdx.x;
  if (tid < 64) ((float4*)hls)[tid] = ((const float4*)(h2 + (size_t)b*256))[tid];
  __syncthreads();
  float acc = b1[tid];
  const float4* w4 = (const float4*)(W1 + (size_t)tid*256);
  const float4* h4 = (const float4*)hls;
  #pragma unroll 8
  for (int k = 0; k < 64; ++k) {
    float4 w = w4[k]; float4 h = h4[k];
    acc = fmaf(w.x,h.x,acc); acc = fmaf(w.y,h.y,acc);
    acc = fmaf(w.z,h.z,acc); acc = fmaf(w.w,h.w,acc);
  }
  red[tid] = fmaxf(acc, 0.0f) * W2[tid];
  __syncthreads();
  for (int s = 64; s > 0; s >>= 1) {
    if (tid < s) red[tid] += red[tid + s];
    __syncthreads();
  }
  if (tid == 0) out[b] = red[0] + b2[0];
}

extern "C" void kernel_launch(void* const* d_in, const int* in_sizes, int n_in,
                              void* d_out, int out_size, void* d_ws, size_t ws_size,
                              hipStream_t stream)
{
  const float* x     = (const float*)d_in[0];
  const float* W_ih0 = (const float*)d_in[1];
  const float* W_hh0 = (const float*)d_in[2];
  const float* b_ih0 = (const float*)d_in[3];
  const float* b_hh0 = (const float*)d_in[4];
  const float* W_ih1 = (const float*)d_in[5];
  const float* W_hh1 = (const float*)d_in[6];
  const float* b_ih1 = (const float*)d_in[7];
  const float* b_hh1 = (const float*)d_in[8];
  const float* W1    = (const float*)d_in[9];
  const float* b1    = (const float*)d_in[10];
  const float* W2    = (const float*)d_in[11];
  const float* b2    = (const float*)d_in[12];

  char* ws = (char*)d_ws;
  uint*    W0i  = (uint*)(ws + OFF_W0);
  uint*    W1i  = (uint*)(ws + OFF_W1);
  uint*    PI0  = (uint*)(ws + OFF_PI0);
  uint*    PI1  = (uint*)(ws + OFF_PI1);
  float*   H2O  = (float*)(ws + OFF_H2O);
  uint*    H1   = (uint*)(ws + OFF_H1);
  ushortt* GX   = (ushortt*)(ws + OFF_GX);

  prep_kernel<<<1248, 256, 0, stream>>>(W_ih0, W_hh0, W_ih1, W_hh1,
                                        W0i, W1i, PI0, PI1);
  gemm0_kernel<<<2048, 512, 0, stream>>>(x, PI0, b_ih0, b_hh0, GX);
  rec_kernel<true><<<BB, 1024, 0, stream>>>(W0i, GX, b_hh0, H1, nullptr);
  gemm1_kernel<<<4096, 1024, 0, stream>>>(H1, PI1, b_ih1, b_hh1, GX);
  rec_kernel<false><<<BB, 1024, 0, stream>>>(W1i, GX, b_hh1, nullptr, H2O);
  mlp_kernel<<<BB, 128, 0, stream>>>(H2O, W1, b1, W2, b2, (float*)d_out);
}